// Round 2
// baseline (133.610 us; speedup 1.0000x reference)
//
#include <hip/hip_runtime.h>
#include <math.h>

#define NT 4096   // B*T tokens
#define DD 128
#define EE 256

// ---- K1: logits[t][e] = bg[e] + sum_d x[t][d] * Wg[d][e] -------------------
// Thread e holds Wg column in VGPRs; 8 tokens per block (512 blocks).
__global__ __launch_bounds__(256) void logits_kernel(
    const float* __restrict__ x, const float* __restrict__ Wg,
    const float* __restrict__ bg, float* __restrict__ logits)
{
    const int e  = threadIdx.x;
    const int t0 = blockIdx.x * 8;
    float wreg[DD];
    #pragma unroll
    for (int d = 0; d < DD; ++d) wreg[d] = Wg[d * EE + e];
    const float be = bg[e];
    for (int tk = 0; tk < 8; ++tk) {
        const int t = t0 + tk;
        const float* xr = x + (size_t)t * DD;
        float acc = be;
        #pragma unroll
        for (int d0 = 0; d0 < DD; d0 += 4) {
            const float4 xv = *reinterpret_cast<const float4*>(xr + d0);
            acc = fmaf(xv.x, wreg[d0 + 0], acc);
            acc = fmaf(xv.y, wreg[d0 + 1], acc);
            acc = fmaf(xv.z, wreg[d0 + 2], acc);
            acc = fmaf(xv.w, wreg[d0 + 3], acc);
        }
        logits[(size_t)t * EE + e] = acc;
    }
}

// ---- K2: top-2 softmax weights, one wave (64 lanes) per token --------------
__global__ __launch_bounds__(256) void top2_kernel(
    const float* __restrict__ logits, int2* __restrict__ idx_out,
    float2* __restrict__ w_out)
{
    const int lane = threadIdx.x & 63;
    const int t    = blockIdx.x * 4 + (threadIdx.x >> 6);
    const float4 lg = *reinterpret_cast<const float4*>(logits + (size_t)t * EE + lane * 4);
    float v[4] = {lg.x, lg.y, lg.z, lg.w};

    // max + argmax (ties -> lowest index, matching jax top_k)
    float m = v[0]; int mi = lane * 4;
    #pragma unroll
    for (int j = 1; j < 4; ++j)
        if (v[j] > m) { m = v[j]; mi = lane * 4 + j; }
    #pragma unroll
    for (int s = 32; s; s >>= 1) {
        const float om = __shfl_xor(m, s);
        const int   oi = __shfl_xor(mi, s);
        if (om > m || (om == m && oi < mi)) { m = om; mi = oi; }
    }

    // softmax denominator
    float ssum = 0.0f;
    #pragma unroll
    for (int j = 0; j < 4; ++j) ssum += __expf(v[j] - m);
    #pragma unroll
    for (int s = 32; s; s >>= 1) ssum += __shfl_xor(ssum, s);

    // second max (exclude mi)
    float m2 = -INFINITY; int mi2 = 0;
    #pragma unroll
    for (int j = 0; j < 4; ++j) {
        const int ei = lane * 4 + j;
        if (ei != mi && v[j] > m2) { m2 = v[j]; mi2 = ei; }
    }
    #pragma unroll
    for (int s = 32; s; s >>= 1) {
        const float om = __shfl_xor(m2, s);
        const int   oi = __shfl_xor(mi2, s);
        if (om > m2 || (om == m2 && oi < mi2)) { m2 = om; mi2 = oi; }
    }

    if (lane == 0) {
        const float p1 = 1.0f / ssum;
        const float p2 = __expf(m2 - m) / ssum;
        const float den = p1 + p2 + 1e-6f;
        idx_out[t] = make_int2(mi, mi2);
        w_out[t]   = make_float2(p1 / den, p2 / den);
    }
}

// ---- K3: expert matvecs, expert-major. Block = (expert, half). -------------
// Thread o holds expert column W[:,o] in 128 VGPRs; self-filters token list.
__global__ __launch_bounds__(128) void expert_kernel(
    const float* __restrict__ x, const float* __restrict__ ew,
    const int2* __restrict__ idx, float* __restrict__ ybuf)
{
    const int e    = blockIdx.x >> 1;
    const int part = blockIdx.x & 1;
    const int o    = threadIdx.x;
    __shared__ int lst[2048];
    __shared__ int cnt;
    if (o == 0) cnt = 0;
    __syncthreads();
    const int base = part * NT;  // flat (token,slot) indices [base, base+4096)
    for (int i = o; i < NT; i += 128) {
        const int fi  = base + i;
        const int tok = fi >> 1, slot = fi & 1;
        const int2 pr = idx[tok];
        const int ee  = slot ? pr.y : pr.x;
        if (ee == e) lst[atomicAdd(&cnt, 1)] = fi;
    }
    __syncthreads();
    const int n = cnt;
    if (n == 0) return;

    const float* W = ew + (size_t)e * DD * DD;
    float wreg[DD];
    #pragma unroll
    for (int d = 0; d < DD; ++d) wreg[d] = W[d * DD + o];

    for (int it = 0; it < n; ++it) {
        const int fi  = lst[it];
        const int tok = fi >> 1;
        const float* xr = x + (size_t)tok * DD;
        float acc = 0.0f;
        #pragma unroll
        for (int d0 = 0; d0 < DD; d0 += 4) {
            const float4 xv = *reinterpret_cast<const float4*>(xr + d0);
            acc = fmaf(xv.x, wreg[d0 + 0], acc);
            acc = fmaf(xv.y, wreg[d0 + 1], acc);
            acc = fmaf(xv.z, wreg[d0 + 2], acc);
            acc = fmaf(xv.w, wreg[d0 + 3], acc);
        }
        ybuf[(size_t)fi * DD + o] = acc;
    }
}

// ---- K4: mixed[t][o] = w.x*y0 + w.y*y1 (elementwise) -----------------------
__global__ __launch_bounds__(256) void mixed_kernel(
    const float* __restrict__ ybuf, const float2* __restrict__ ww,
    float* __restrict__ mixed)
{
    const int i = blockIdx.x * 256 + threadIdx.x;  // one float4 per thread
    const int t = i >> 5;
    const int c = (i & 31) * 4;
    const float2 w = ww[t];
    const float4 a = *reinterpret_cast<const float4*>(ybuf + (size_t)(t * 2 + 0) * DD + c);
    const float4 b = *reinterpret_cast<const float4*>(ybuf + (size_t)(t * 2 + 1) * DD + c);
    float4 r;
    r.x = w.x * a.x + w.y * b.x;
    r.y = w.x * a.y + w.y * b.y;
    r.z = w.x * a.z + w.y * b.z;
    r.w = w.x * a.w + w.y * b.w;
    *reinterpret_cast<float4*>(mixed + (size_t)t * DD + c) = r;
}

// ---- K5: SwiGLU + variance consensus. Thread holds w1 OR w2 column. --------
__global__ __launch_bounds__(256) void swiglu_kernel(
    const float* __restrict__ mixed, const float* __restrict__ w1,
    const float* __restrict__ b1, const float* __restrict__ w2,
    const float* __restrict__ b2, const float* __restrict__ ybuf,
    const float2* __restrict__ ww, float* __restrict__ out_avg,
    float* __restrict__ out_cons)
{
    const int o     = threadIdx.x & 127;
    const int which = threadIdx.x >> 7;   // 0 -> w1/g, 1 -> w2/h
    const int t0    = blockIdx.x * 8;
    const float* Wc = which ? w2 : w1;
    const float bias = which ? b2[o] : b1[o];
    float wreg[DD];
    #pragma unroll
    for (int d = 0; d < DD; ++d) wreg[d] = Wc[d * DD + o];

    __shared__ float hs[DD];
    __shared__ float vred[2];

    for (int tk = 0; tk < 8; ++tk) {
        const int t = t0 + tk;
        const float* mr = mixed + (size_t)t * DD;
        float acc = bias;
        #pragma unroll
        for (int d0 = 0; d0 < DD; d0 += 4) {
            const float4 mv = *reinterpret_cast<const float4*>(mr + d0);
            acc = fmaf(mv.x, wreg[d0 + 0], acc);
            acc = fmaf(mv.y, wreg[d0 + 1], acc);
            acc = fmaf(mv.z, wreg[d0 + 2], acc);
            acc = fmaf(mv.w, wreg[d0 + 3], acc);
        }
        if (which) hs[o] = acc;
        __syncthreads();
        if (!which) {
            const float g   = acc, hv = hs[o];
            const float sig = 1.0f / (1.0f + __expf(-g));
            const float wavg = g * sig * hv;
            out_avg[(size_t)t * DD + o] = wavg;
            const float2 w = ww[t];
            const float ya = ybuf[(size_t)(t * 2 + 0) * DD + o];
            const float yb = ybuf[(size_t)(t * 2 + 1) * DD + o];
            const float da = ya - wavg, db = yb - wavg;
            float v = w.x * da * da + w.y * db * db;
            #pragma unroll
            for (int s = 32; s; s >>= 1) v += __shfl_down(v, s);
            if ((o & 63) == 0) vred[o >> 6] = v;
        }
        __syncthreads();
        if (threadIdx.x == 0)
            out_cons[t] = __expf(-(vred[0] + vred[1]) * (1.0f / DD));
        __syncthreads();
    }
}

extern "C" void kernel_launch(void* const* d_in, const int* in_sizes, int n_in,
                              void* d_out, int out_size, void* d_ws, size_t ws_size,
                              hipStream_t stream) {
    const float* x   = (const float*)d_in[0];
    const float* Wg  = (const float*)d_in[1];
    const float* bg  = (const float*)d_in[2];
    const float* ew  = (const float*)d_in[3];
    const float* w1  = (const float*)d_in[4];
    const float* b1  = (const float*)d_in[5];
    const float* w2  = (const float*)d_in[6];
    const float* b2  = (const float*)d_in[7];

    float* out_avg  = (float*)d_out;              // [NT, D]
    float* out_cons = out_avg + (size_t)NT * DD;  // [NT]

    // ws layout: logits (4 MB, reused as ybuf) | idx 32KB | ww 32KB | mixed 2MB
    char* ws = (char*)d_ws;
    float*  logits = (float*)ws;                       // [NT,EE] -> later [NT,2,DD]
    float*  ybuf   = logits;                           // alias (logits dead after top2)
    int2*   idx    = (int2*)(ws + 4 * 1024 * 1024);
    float2* wwp    = (float2*)(ws + 4 * 1024 * 1024 + 32 * 1024);
    float*  mixed  = (float*)(ws + 4 * 1024 * 1024 + 64 * 1024);

    logits_kernel<<<NT / 8, 256, 0, stream>>>(x, Wg, bg, logits);
    top2_kernel  <<<NT / 4, 256, 0, stream>>>(logits, idx, wwp);
    expert_kernel<<<EE * 2, 128, 0, stream>>>(x, ew, idx, ybuf);
    mixed_kernel <<<NT * DD / 4 / 256, 256, 0, stream>>>(ybuf, wwp, mixed);
    swiglu_kernel<<<NT / 8, 256, 0, stream>>>(mixed, w1, b1, w2, b2, ybuf, wwp,
                                              out_avg, out_cons);
}

// Round 3
// 97.319 us; speedup vs baseline: 1.3729x; 1.3729x over previous
//
#include <hip/hip_runtime.h>
#include <math.h>

#define NT  4096   // B*T tokens
#define DD  128
#define EE  256
#define CAP 2048   // per-expert pair-list capacity (observed max ~60)

// ---- K1: logits[t][e] = bg[e] + sum_d x[t][d] * Wg[d][e] -------------------
// Thread e holds Wg column in VGPRs; 8 tokens per block, 2-token ILP.
__global__ __launch_bounds__(256) void logits_kernel(
    const float* __restrict__ x, const float* __restrict__ Wg,
    const float* __restrict__ bg, float* __restrict__ logits)
{
    const int e  = threadIdx.x;
    const int t0 = blockIdx.x * 8;
    float wreg[DD];
    #pragma unroll
    for (int d = 0; d < DD; ++d) wreg[d] = Wg[d * EE + e];
    const float be = bg[e];
    for (int tk = 0; tk < 8; tk += 2) {
        const float* xr0 = x + (size_t)(t0 + tk) * DD;
        const float* xr1 = xr0 + DD;
        float a0 = be, a1 = be;
        #pragma unroll
        for (int d0 = 0; d0 < DD; d0 += 4) {
            const float4 v0 = *reinterpret_cast<const float4*>(xr0 + d0);
            const float4 v1 = *reinterpret_cast<const float4*>(xr1 + d0);
            a0 = fmaf(v0.x, wreg[d0 + 0], a0);  a1 = fmaf(v1.x, wreg[d0 + 0], a1);
            a0 = fmaf(v0.y, wreg[d0 + 1], a0);  a1 = fmaf(v1.y, wreg[d0 + 1], a1);
            a0 = fmaf(v0.z, wreg[d0 + 2], a0);  a1 = fmaf(v1.z, wreg[d0 + 2], a1);
            a0 = fmaf(v0.w, wreg[d0 + 3], a0);  a1 = fmaf(v1.w, wreg[d0 + 3], a1);
        }
        logits[(size_t)(t0 + tk) * EE + e]     = a0;
        logits[(size_t)(t0 + tk + 1) * EE + e] = a1;
    }
}

// ---- K2: top-2 softmax weights + scatter pairs into per-expert lists -------
// One wave (64 lanes) per token, 4 tokens per block.
__global__ __launch_bounds__(256) void top2_kernel(
    const float* __restrict__ logits, float2* __restrict__ w_out,
    int* __restrict__ cnt, int* __restrict__ plist)
{
    const int lane = threadIdx.x & 63;
    const int t    = blockIdx.x * 4 + (threadIdx.x >> 6);
    const float4 lg = *reinterpret_cast<const float4*>(logits + (size_t)t * EE + lane * 4);
    float v[4] = {lg.x, lg.y, lg.z, lg.w};

    // max + argmax (ties -> lowest index, matching jax top_k)
    float m = v[0]; int mi = lane * 4;
    #pragma unroll
    for (int j = 1; j < 4; ++j)
        if (v[j] > m) { m = v[j]; mi = lane * 4 + j; }
    #pragma unroll
    for (int s = 32; s; s >>= 1) {
        const float om = __shfl_xor(m, s);
        const int   oi = __shfl_xor(mi, s);
        if (om > m || (om == m && oi < mi)) { m = om; mi = oi; }
    }

    // softmax denominator
    float ssum = 0.0f;
    #pragma unroll
    for (int j = 0; j < 4; ++j) ssum += __expf(v[j] - m);
    #pragma unroll
    for (int s = 32; s; s >>= 1) ssum += __shfl_xor(ssum, s);

    // second max (exclude mi)
    float m2 = -INFINITY; int mi2 = 0;
    #pragma unroll
    for (int j = 0; j < 4; ++j) {
        const int ei = lane * 4 + j;
        if (ei != mi && v[j] > m2) { m2 = v[j]; mi2 = ei; }
    }
    #pragma unroll
    for (int s = 32; s; s >>= 1) {
        const float om = __shfl_xor(m2, s);
        const int   oi = __shfl_xor(mi2, s);
        if (om > m2 || (om == m2 && oi < mi2)) { m2 = om; mi2 = oi; }
    }

    if (lane == 0) {
        const float p1 = 1.0f / ssum;
        const float p2 = __expf(m2 - m) / ssum;
        const float den = p1 + p2 + 1e-6f;
        w_out[t] = make_float2(p1 / den, p2 / den);
        const int pos1 = atomicAdd(&cnt[mi], 1);
        if (pos1 < CAP) plist[mi * CAP + pos1] = t * 2;       // slot 0
        const int pos2 = atomicAdd(&cnt[mi2], 1);
        if (pos2 < CAP) plist[mi2 * CAP + pos2] = t * 2 + 1;  // slot 1
    }
}

// ---- K3: expert matvecs. 8 blocks per expert, XCD-chunk swizzled. ----------
__global__ __launch_bounds__(128) void expert_kernel(
    const float* __restrict__ x, const float* __restrict__ ew,
    const int* __restrict__ cnt, const int* __restrict__ plist,
    float* __restrict__ ybuf)
{
    // bijective swizzle: 256 consecutive logical blocks (32 experts) per XCD
    const int wg = (blockIdx.x & 7) * 256 + (blockIdx.x >> 3);
    const int e  = wg >> 3;
    const int j  = wg & 7;
    int n = cnt[e];
    if (n > CAP) n = CAP;
    if (j >= n) return;

    const int o = threadIdx.x;
    const float* W = ew + (size_t)e * DD * DD;
    float wreg[DD];
    #pragma unroll
    for (int d = 0; d < DD; ++d) wreg[d] = W[d * DD + o];

    for (int it = j; it < n; it += 8) {
        const int fi = plist[e * CAP + it];
        const float* xr = x + (size_t)(fi >> 1) * DD;
        float acc = 0.0f;
        #pragma unroll
        for (int d0 = 0; d0 < DD; d0 += 4) {
            const float4 xv = *reinterpret_cast<const float4*>(xr + d0);
            acc = fmaf(xv.x, wreg[d0 + 0], acc);
            acc = fmaf(xv.y, wreg[d0 + 1], acc);
            acc = fmaf(xv.z, wreg[d0 + 2], acc);
            acc = fmaf(xv.w, wreg[d0 + 3], acc);
        }
        ybuf[(size_t)fi * DD + o] = acc;
    }
}

// ---- K4: mixed + SwiGLU + variance consensus (fused). ----------------------
// 256 threads: o = tid&127 (output dim), which = tid>>7 (0->w1/g, 1->w2/h).
__global__ __launch_bounds__(256) void swiglu_kernel(
    const float* __restrict__ ybuf, const float2* __restrict__ ww,
    const float* __restrict__ w1, const float* __restrict__ b1,
    const float* __restrict__ w2, const float* __restrict__ b2,
    float* __restrict__ out_avg, float* __restrict__ out_cons)
{
    const int o     = threadIdx.x & 127;
    const int which = threadIdx.x >> 7;
    const int t0    = blockIdx.x * 8;
    const float* Wc  = which ? w2 : w1;
    const float bias = which ? b2[o] : b1[o];
    float wreg[DD];
    #pragma unroll
    for (int d = 0; d < DD; ++d) wreg[d] = Wc[d * DD + o];

    __shared__ float ms[DD];
    __shared__ float hs[DD];
    __shared__ float vred[2];

    for (int tk = 0; tk < 8; ++tk) {
        const int t = t0 + tk;
        const float2 w = ww[t];
        const float ya = ybuf[(size_t)(2 * t) * DD + o];
        const float yb = ybuf[(size_t)(2 * t + 1) * DD + o];
        const float mx = w.x * ya + w.y * yb;
        if (!which) ms[o] = mx;
        __syncthreads();

        float acc = bias;
        #pragma unroll
        for (int d0 = 0; d0 < DD; d0 += 4) {
            const float4 mv = *reinterpret_cast<const float4*>(ms + d0);
            acc = fmaf(mv.x, wreg[d0 + 0], acc);
            acc = fmaf(mv.y, wreg[d0 + 1], acc);
            acc = fmaf(mv.z, wreg[d0 + 2], acc);
            acc = fmaf(mv.w, wreg[d0 + 3], acc);
        }
        if (which) hs[o] = acc;
        __syncthreads();

        if (!which) {
            const float g   = acc, hv = hs[o];
            const float sig = 1.0f / (1.0f + __expf(-g));
            const float wavg = g * sig * hv;
            out_avg[(size_t)t * DD + o] = wavg;
            const float da = ya - wavg, db = yb - wavg;
            float v = w.x * da * da + w.y * db * db;
            #pragma unroll
            for (int s = 32; s; s >>= 1) v += __shfl_down(v, s);
            if ((o & 63) == 0) vred[o >> 6] = v;
        }
        __syncthreads();
        if (threadIdx.x == 0)
            out_cons[t] = __expf(-(vred[0] + vred[1]) * (1.0f / DD));
        __syncthreads();
    }
}

extern "C" void kernel_launch(void* const* d_in, const int* in_sizes, int n_in,
                              void* d_out, int out_size, void* d_ws, size_t ws_size,
                              hipStream_t stream) {
    const float* x   = (const float*)d_in[0];
    const float* Wg  = (const float*)d_in[1];
    const float* bg  = (const float*)d_in[2];
    const float* ew  = (const float*)d_in[3];
    const float* w1  = (const float*)d_in[4];
    const float* b1  = (const float*)d_in[5];
    const float* w2  = (const float*)d_in[6];
    const float* b2  = (const float*)d_in[7];

    float* out_avg  = (float*)d_out;              // [NT, D]
    float* out_cons = out_avg + (size_t)NT * DD;  // [NT]

    // ws layout: logits 4MB (aliased by ybuf) | ww 32KB | cnt 4KB(pad) | plist 2MB
    char* ws = (char*)d_ws;
    float*  logits = (float*)ws;                           // [NT,EE]
    float*  ybuf   = logits;                               // [NT*2,DD] alias
    float2* wwp    = (float2*)(ws + 4 * 1024 * 1024);
    int*    cnt    = (int*)   (ws + 4 * 1024 * 1024 + 32 * 1024);
    int*    plist  = (int*)   (ws + 4 * 1024 * 1024 + 64 * 1024);  // [EE,CAP]

    hipMemsetAsync(cnt, 0, EE * sizeof(int), stream);
    logits_kernel<<<NT / 8, 256, 0, stream>>>(x, Wg, bg, logits);
    top2_kernel  <<<NT / 4, 256, 0, stream>>>(logits, wwp, cnt, plist);
    expert_kernel<<<EE * 8, 128, 0, stream>>>(x, ew, cnt, plist, ybuf);
    swiglu_kernel<<<NT / 8, 256, 0, stream>>>(ybuf, wwp, w1, b1, w2, b2,
                                              out_avg, out_cons);
}

// Round 5
// 76.623 us; speedup vs baseline: 1.7437x; 1.2701x over previous
//
#include <hip/hip_runtime.h>
#include <math.h>

#define NT  4096   // B*T tokens
#define DD  128
#define EE  256
#define CAP 2048   // per-expert pair-list capacity (observed max ~60)
#define RB  (NT/8) // 512 logits blocks
#define PFB 1024   // prefetch blocks (128 per XCD)

// ---- K0: zero the per-expert counters (replaces 40us blit memset) ----------
__global__ void zero_kernel(int* __restrict__ cnt) { cnt[threadIdx.x] = 0; }

// ---- K1: logits[t][e] = bg[e] + sum_d x[t][d]*Wg[d][e], + ew L2 prefetch ---
__global__ __launch_bounds__(256) void logits_kernel(
    const float* __restrict__ x, const float* __restrict__ Wg,
    const float* __restrict__ bg, const float* __restrict__ ew,
    float* __restrict__ logits)
{
    const int bid = blockIdx.x;
    if (bid >= RB) {
        // Prefetch an XCD's 32-expert slice (2 MB) into its L2. Blocks land
        // round-robin on XCD (bid&7); expert_kernel's swizzle uses the same
        // mapping. Wrong mapping costs speed only, never correctness.
        const int pb  = bid - RB;          // 0..1023
        const int xcd = bid & 7;
        const int c   = pb >> 3;           // 0..127: 16KB chunk within slice
        const float4* src = reinterpret_cast<const float4*>(ew)
                          + (size_t)xcd * (32 * DD * DD / 4);
        float s = 0.0f;
        #pragma unroll
        for (int q = 0; q < 4; ++q) {
            const float4 v = src[(size_t)c * 1024 + q * 256 + threadIdx.x];
            s += v.x + v.y + v.z + v.w;
        }
        asm volatile("" :: "v"(s));  // keep loads live (rule #17)
        return;
    }

    const int e  = threadIdx.x;
    const int t0 = bid * 8;
    float wreg[DD];
    #pragma unroll
    for (int d = 0; d < DD; ++d) wreg[d] = Wg[d * EE + e];
    const float be = bg[e];
    for (int tk = 0; tk < 8; tk += 2) {
        const float* xr0 = x + (size_t)(t0 + tk) * DD;
        const float* xr1 = xr0 + DD;
        float a0 = be, a1 = be;
        #pragma unroll
        for (int d0 = 0; d0 < DD; d0 += 4) {
            const float4 v0 = *reinterpret_cast<const float4*>(xr0 + d0);
            const float4 v1 = *reinterpret_cast<const float4*>(xr1 + d0);
            a0 = fmaf(v0.x, wreg[d0 + 0], a0);  a1 = fmaf(v1.x, wreg[d0 + 0], a1);
            a0 = fmaf(v0.y, wreg[d0 + 1], a0);  a1 = fmaf(v1.y, wreg[d0 + 1], a1);
            a0 = fmaf(v0.z, wreg[d0 + 2], a0);  a1 = fmaf(v1.z, wreg[d0 + 2], a1);
            a0 = fmaf(v0.w, wreg[d0 + 3], a0);  a1 = fmaf(v1.w, wreg[d0 + 3], a1);
        }
        logits[(size_t)(t0 + tk) * EE + e]     = a0;
        logits[(size_t)(t0 + tk + 1) * EE + e] = a1;
    }
}

// ---- K2: top-2 softmax weights + scatter pairs into per-expert lists -------
// One wave (64 lanes) per token, 4 tokens per block. (round-3 proven)
__global__ __launch_bounds__(256) void top2_kernel(
    const float* __restrict__ logits, float2* __restrict__ w_out,
    int* __restrict__ cnt, int* __restrict__ plist)
{
    const int lane = threadIdx.x & 63;
    const int t    = blockIdx.x * 4 + (threadIdx.x >> 6);
    const float4 lg = *reinterpret_cast<const float4*>(logits + (size_t)t * EE + lane * 4);
    float v[4] = {lg.x, lg.y, lg.z, lg.w};

    // max + argmax (ties -> lowest index, matching jax top_k)
    float m = v[0]; int mi = lane * 4;
    #pragma unroll
    for (int j = 1; j < 4; ++j)
        if (v[j] > m) { m = v[j]; mi = lane * 4 + j; }
    #pragma unroll
    for (int s = 32; s; s >>= 1) {
        const float om = __shfl_xor(m, s);
        const int   oi = __shfl_xor(mi, s);
        if (om > m || (om == m && oi < mi)) { m = om; mi = oi; }
    }

    // softmax denominator
    float ssum = 0.0f;
    #pragma unroll
    for (int j = 0; j < 4; ++j) ssum += __expf(v[j] - m);
    #pragma unroll
    for (int s = 32; s; s >>= 1) ssum += __shfl_xor(ssum, s);

    // second max (exclude mi)
    float m2 = -INFINITY; int mi2 = 0;
    #pragma unroll
    for (int j = 0; j < 4; ++j) {
        const int ei = lane * 4 + j;
        if (ei != mi && v[j] > m2) { m2 = v[j]; mi2 = ei; }
    }
    #pragma unroll
    for (int s = 32; s; s >>= 1) {
        const float om = __shfl_xor(m2, s);
        const int   oi = __shfl_xor(mi2, s);
        if (om > m2 || (om == m2 && oi < mi2)) { m2 = om; mi2 = oi; }
    }

    if (lane == 0) {
        const float p1 = 1.0f / ssum;
        const float p2 = __expf(m2 - m) / ssum;
        const float den = p1 + p2 + 1e-6f;
        w_out[t] = make_float2(p1 / den, p2 / den);
        const int pos1 = atomicAdd(&cnt[mi], 1);
        if (pos1 < CAP) plist[mi * CAP + pos1] = t * 2;       // slot 0
        const int pos2 = atomicAdd(&cnt[mi2], 1);
        if (pos2 < CAP) plist[mi2 * CAP + pos2] = t * 2 + 1;  // slot 1
    }
}

// ---- K3: expert matvecs, 8 blocks/expert, dual-pair ILP, XCD swizzle -------
__global__ __launch_bounds__(128) void expert_kernel(
    const float* __restrict__ x, const float* __restrict__ ew,
    const int* __restrict__ cnt, const int* __restrict__ plist,
    float* __restrict__ ybuf)
{
    // bijective swizzle: 256 consecutive logical wgs (32 experts) per XCD
    const int wg = (blockIdx.x & 7) * 256 + (blockIdx.x >> 3);
    const int e  = wg >> 3;
    const int j  = wg & 7;
    int n = cnt[e];
    if (n > CAP) n = CAP;
    if (j >= n) return;

    const int o = threadIdx.x;
    const float* W = ew + (size_t)e * DD * DD;
    float wreg[DD];
    #pragma unroll
    for (int d = 0; d < DD; ++d) wreg[d] = W[d * DD + o];  // L2-warm (prefetched)

    for (int base = j; base < n; base += 16) {
        const int i1 = base + 8;
        const int f0 = plist[e * CAP + base];
        const int f1 = (i1 < n) ? plist[e * CAP + i1] : f0;
        const float* x0 = x + (size_t)(f0 >> 1) * DD;
        const float* x1 = x + (size_t)(f1 >> 1) * DD;
        float acc0 = 0.0f, acc1 = 0.0f;   // two independent chains
        #pragma unroll
        for (int d0 = 0; d0 < DD; d0 += 4) {
            const float4 v0 = *reinterpret_cast<const float4*>(x0 + d0);
            const float4 v1 = *reinterpret_cast<const float4*>(x1 + d0);
            acc0 = fmaf(v0.x, wreg[d0 + 0], acc0);  acc1 = fmaf(v1.x, wreg[d0 + 0], acc1);
            acc0 = fmaf(v0.y, wreg[d0 + 1], acc0);  acc1 = fmaf(v1.y, wreg[d0 + 1], acc1);
            acc0 = fmaf(v0.z, wreg[d0 + 2], acc0);  acc1 = fmaf(v1.z, wreg[d0 + 2], acc1);
            acc0 = fmaf(v0.w, wreg[d0 + 3], acc0);  acc1 = fmaf(v1.w, wreg[d0 + 3], acc1);
        }
        ybuf[(size_t)f0 * DD + o] = acc0;
        if (i1 < n) ybuf[(size_t)f1 * DD + o] = acc1;
    }
}

// ---- K4: mixed + SwiGLU + variance consensus (round-3 proven, 4 barriers) --
__global__ __launch_bounds__(256) void swiglu_kernel(
    const float* __restrict__ ybuf, const float2* __restrict__ ww,
    const float* __restrict__ w1, const float* __restrict__ b1,
    const float* __restrict__ w2, const float* __restrict__ b2,
    float* __restrict__ out_avg, float* __restrict__ out_cons)
{
    const int o     = threadIdx.x & 127;
    const int which = threadIdx.x >> 7;
    const int t0    = blockIdx.x * 8;
    const float* Wc  = which ? w2 : w1;
    const float bias = which ? b2[o] : b1[o];
    float wreg[DD];
    #pragma unroll
    for (int d = 0; d < DD; ++d) wreg[d] = Wc[d * DD + o];

    __shared__ float ms[DD];
    __shared__ float hs[DD];
    __shared__ float vred[2];

    for (int tk = 0; tk < 8; ++tk) {
        const int t = t0 + tk;
        const float2 w = ww[t];
        const float ya = ybuf[(size_t)(2 * t) * DD + o];
        const float yb = ybuf[(size_t)(2 * t + 1) * DD + o];
        const float mx = w.x * ya + w.y * yb;
        if (!which) ms[o] = mx;
        __syncthreads();

        float acc = bias;
        #pragma unroll
        for (int d0 = 0; d0 < DD; d0 += 4) {
            const float4 mv = *reinterpret_cast<const float4*>(ms + d0);
            acc = fmaf(mv.x, wreg[d0 + 0], acc);
            acc = fmaf(mv.y, wreg[d0 + 1], acc);
            acc = fmaf(mv.z, wreg[d0 + 2], acc);
            acc = fmaf(mv.w, wreg[d0 + 3], acc);
        }
        if (which) hs[o] = acc;
        __syncthreads();

        if (!which) {
            const float g   = acc, hv = hs[o];
            const float sig = 1.0f / (1.0f + __expf(-g));
            const float wavg = g * sig * hv;
            out_avg[(size_t)t * DD + o] = wavg;
            const float da = ya - wavg, db = yb - wavg;
            float v = w.x * da * da + w.y * db * db;
            #pragma unroll
            for (int s = 32; s; s >>= 1) v += __shfl_down(v, s);
            if ((o & 63) == 0) vred[o >> 6] = v;
        }
        __syncthreads();
        if (threadIdx.x == 0)
            out_cons[t] = __expf(-(vred[0] + vred[1]) * (1.0f / DD));
        __syncthreads();
    }
}

extern "C" void kernel_launch(void* const* d_in, const int* in_sizes, int n_in,
                              void* d_out, int out_size, void* d_ws, size_t ws_size,
                              hipStream_t stream) {
    const float* x   = (const float*)d_in[0];
    const float* Wg  = (const float*)d_in[1];
    const float* bg  = (const float*)d_in[2];
    const float* ew  = (const float*)d_in[3];
    const float* w1  = (const float*)d_in[4];
    const float* b1  = (const float*)d_in[5];
    const float* w2  = (const float*)d_in[6];
    const float* b2  = (const float*)d_in[7];

    float* out_avg  = (float*)d_out;              // [NT, D]
    float* out_cons = out_avg + (size_t)NT * DD;  // [NT]

    // ws layout (round-3 proven): logits 4MB (aliased by ybuf) | ww 32KB |
    // cnt 32KB(pad) | plist 2MB
    char* ws = (char*)d_ws;
    float*  logits = (float*)ws;                           // [NT,EE]
    float*  ybuf   = logits;                               // [NT*2,DD] alias
    float2* wwp    = (float2*)(ws + 4 * 1024 * 1024);
    int*    cnt    = (int*)   (ws + 4 * 1024 * 1024 + 32 * 1024);
    int*    plist  = (int*)   (ws + 4 * 1024 * 1024 + 64 * 1024);  // [EE,CAP]

    zero_kernel  <<<1, EE, 0, stream>>>(cnt);
    logits_kernel<<<RB + PFB, 256, 0, stream>>>(x, Wg, bg, ew, logits);
    top2_kernel  <<<NT / 4, 256, 0, stream>>>(logits, wwp, cnt, plist);
    expert_kernel<<<EE * 8, 128, 0, stream>>>(x, ew, cnt, plist, ybuf);
    swiglu_kernel<<<NT / 8, 256, 0, stream>>>(ybuf, wwp, w1, b1, w2, b2,
                                              out_avg, out_cons);
}